// Round 3
// baseline (343.994 us; speedup 1.0000x reference)
//
#include <hip/hip_runtime.h>

#define NODES 16384
#define NF 64
#define NBLK 128          // nodes per workgroup (main kernel)
#define TROW 72           // shorts per tbuf row (64 data + 8 pad) = 144 B
#define BATCH 32

// ws layout (bytes):
//   wbf  bf16 @0        (122,880)
//   wt   fp32 @122,880  (245,760)   W^T per level: [k][i][o]
//   bpre fp32 @368,640  (3,840)
//   far  fp32 @372,480  (1,048,576) per (b, nblk): sum_{k=8..L} W_k@x[n0>>k] + bpre[L]
#define WS_WBF_OFF   0ull
#define WS_WT_OFF    122880ull
#define WS_BPRE_OFF  368640ull
#define WS_FAR_OFF   372480ull
#define WS_NEEDED    1421056ull

typedef __attribute__((ext_vector_type(8))) short short8;
typedef __attribute__((ext_vector_type(4))) short shortx4;
typedef __attribute__((ext_vector_type(4))) float floatx4;

__device__ __forceinline__ short f2bf(float f) {
    unsigned u = __float_as_uint(f);
    u += 0x7fffu + ((u >> 16) & 1u);          // RTNE (inputs finite)
    return (short)(u >> 16);
}
__device__ __forceinline__ float bf2f(short s) {
    return __uint_as_float(((unsigned)(unsigned short)s) << 16);
}
__device__ __forceinline__ short8 cvt8(floatx4 a, floatx4 c) {
    short8 r;
    r[0]=f2bf(a[0]); r[1]=f2bf(a[1]); r[2]=f2bf(a[2]); r[3]=f2bf(a[3]);
    r[4]=f2bf(c[0]); r[5]=f2bf(c[1]); r[6]=f2bf(c[2]); r[7]=f2bf(c[3]);
    return r;
}

// ---------------------------------------------------------------------------
// prep1: W fp32 -> bf16 (blocks 0..29), bias prefix (block 30),
//        W^T fp32 [k][i][o] (blocks 31..45) for coalesced matvecs in prep2.
// ---------------------------------------------------------------------------
__global__ __launch_bounds__(256)
void heaplin_prep1(const float* __restrict__ W, const float* __restrict__ bias,
                   short* __restrict__ wbf, float* __restrict__ wt,
                   float* __restrict__ bpre)
{
    const int blk = blockIdx.x;
    const int tid = threadIdx.x;
    if (blk < 30) {
        int e = blk * 2048 + tid * 8;        // [0, 61440)
        floatx4 a = *(const floatx4*)(W + e);
        floatx4 c = *(const floatx4*)(W + e + 4);
        *(short8*)(wbf + e) = cvt8(a, c);
    } else if (blk == 30) {
        if (tid < 64) {
            float run = 0.f;
            for (int k = 0; k < 15; ++k) { run += bias[k * 64 + tid]; bpre[k * 64 + tid] = run; }
        }
    } else {
        int k = blk - 31;                    // 0..14
        #pragma unroll
        for (int it = 0; it < 16; ++it) {
            int idx = tid + it * 256;        // [0, 4096)
            int o = idx >> 6, i = idx & 63;
            wt[k * 4096 + i * 64 + o] = W[k * 4096 + idx];
        }
    }
}

// ---------------------------------------------------------------------------
// prep2: far-ancestor table, fp32-exact (precision-critical path).
// One block per batch b. Z[t][a] = W[7+t] @ x[b][a] for a in [0, 128>>t),
// packed rows at base(t) = 128 - (128>>(t-1)).  Then
//   far[b][m][o] = sum_{t=1..bitlen(m)} Z[t][m>>t][o] + bpre[(7+bitlen(m))*64+o].
// ---------------------------------------------------------------------------
__global__ __launch_bounds__(256)
void heaplin_prep2(const float* __restrict__ x, const float* __restrict__ wt,
                   const float* __restrict__ bpre, float* __restrict__ far)
{
    __shared__ float xl[64 * 64];            // x rows 0..63
    __shared__ float Zl[127 * 64];           // packed Z rows
    const int tid = threadIdx.x;
    const int b   = blockIdx.x;
    const float* xb = x + (size_t)b * NODES * NF;

    #pragma unroll
    for (int i = 0; i < 4; ++i) {            // stage 16 KB coalesced
        int job = tid + i * 256;             // 1024 floatx4 jobs
        *(floatx4*)(xl + job * 4) = *(const floatx4*)(xb + job * 4);
    }
    __syncthreads();

    const int wave = tid >> 6, lane = tid & 63;
    const int o4 = lane & 15, j = lane >> 4;
    for (int r = wave; r < 127; r += 4) {
        int t, a;
        if (r < 64)       { t = 1; a = r; }
        else if (r < 96)  { t = 2; a = r - 64; }
        else if (r < 112) { t = 3; a = r - 96; }
        else if (r < 120) { t = 4; a = r - 112; }
        else if (r < 124) { t = 5; a = r - 120; }
        else if (r < 126) { t = 6; a = r - 124; }
        else              { t = 7; a = 0; }
        const float* wtk = wt + (7 + t) * 4096;
        floatx4 acc = {0.f, 0.f, 0.f, 0.f};
        #pragma unroll
        for (int i16 = 0; i16 < 16; ++i16) {
            int i = j + i16 * 4;             // j splits the i-dim 4 ways
            floatx4 w4 = *(const floatx4*)(wtk + i * 64 + o4 * 4);
            float xs = xl[a * 64 + i];
            acc[0] += w4[0]*xs; acc[1] += w4[1]*xs; acc[2] += w4[2]*xs; acc[3] += w4[3]*xs;
        }
        #pragma unroll
        for (int c = 0; c < 4; ++c) {        // reduce over j (lanes ^16, ^32)
            acc[c] += __shfl_xor(acc[c], 16, 64);
            acc[c] += __shfl_xor(acc[c], 32, 64);
        }
        if (j == 0) *(floatx4*)(Zl + r * 64 + o4 * 4) = acc;
    }
    __syncthreads();

    for (int it = 0; it < 32; ++it) {
        int job = tid + it * 256;
        if (job < 127 * 64) {
            int m = 1 + (job >> 6), o = job & 63;
            int bl = 32 - __clz(m);          // 1..7
            float s = bpre[(7 + bl) * 64 + o];
            #pragma unroll
            for (int t = 1; t <= 7; ++t)
                if (t <= bl) s += Zl[(128 - (128 >> (t - 1)) + (m >> t)) * 64 + o];
            far[((size_t)b * 128 + m) * 64 + o] = s;
        }
    }
}

// ---------------------------------------------------------------------------
// Main kernel. All MFMAs use SWAPPED operands: mfma(b_frag, a_frag) = (A.B)^T,
// so each lane owns one node row (lr) and 4 consecutive feature cols
// (lq*4+rg). Epilogue becomes dwordx4 stores; LDS traffic becomes b64/b128.
// ---------------------------------------------------------------------------
__global__ __launch_bounds__(256, 2)
void heaplin_main(const float* __restrict__ x, const short* __restrict__ wbf,
                  const float* __restrict__ far, const float* __restrict__ bpre,
                  float* __restrict__ out)
{
    __shared__ short tbuf[128 * TROW];       // main: t1..t7 rows 0..126; block0: stage rows 0..127

    const int tid  = threadIdx.x;
    const int lane = tid & 63;
    const int wave = tid >> 6;
    const int lr = lane & 15;
    const int lq = lane >> 4;
    const int nblk = blockIdx.x;
    const int b    = blockIdx.y;
    const float* xb = x + (size_t)b * NODES * NF;
    float* ob = out + (size_t)b * NODES * NF;
    const floatx4 zero4 = {0.f, 0.f, 0.f, 0.f};

    if (nblk == 0) {
        // ---------- block-0 path: nodes 0..127 span levels 0..7 (masked) ----------
        floatx4 accE[8];
        #pragma unroll
        for (int t8 = 0; t8 < 8; ++t8) accE[t8] = zero4;

        for (int k = 0; k < 8; ++k) {
            __syncthreads();
            #pragma unroll
            for (int i = 0; i < 8; ++i) {    // 2048 jobs: stage row j = x[j>>k] or 0
                int job = tid + i * 256;
                int r = job >> 4, c4 = job & 15;
                bool valid = (k == 0) || (r >= (1 << (k - 1)));
                floatx4 vv = zero4;
                if (valid) vv = *(const floatx4*)(xb + (r >> k) * NF + c4 * 4);
                shortx4 s4;
                s4[0]=f2bf(vv[0]); s4[1]=f2bf(vv[1]); s4[2]=f2bf(vv[2]); s4[3]=f2bf(vv[3]);
                *(shortx4*)(tbuf + r * TROW + c4 * 4) = s4;
            }
            __syncthreads();
            #pragma unroll
            for (int t8 = 0; t8 < 8; ++t8) {
                int mt = 2 * wave + (t8 & 1);
                int nt = t8 >> 1;
                int arow = mt * 16 + lr;
                const short* wp = wbf + k * 4096 + (nt * 16 + lr) * 64 + lq * 8;
                short8 b0 = *(const short8*)wp;
                short8 b1 = *(const short8*)(wp + 32);
                short8 a0 = *(const short8*)(tbuf + arow * TROW + lq * 8);
                short8 a1 = *(const short8*)(tbuf + arow * TROW + 32 + lq * 8);
                accE[t8] = __builtin_amdgcn_mfma_f32_16x16x32_bf16(b0, a0, accE[t8], 0, 0, 0);
                accE[t8] = __builtin_amdgcn_mfma_f32_16x16x32_bf16(b1, a1, accE[t8], 0, 0, 0);
            }
        }
        #pragma unroll
        for (int t8 = 0; t8 < 8; ++t8) {
            int mt = 2 * wave + (t8 & 1);
            int nt = t8 >> 1;
            int j  = mt * 16 + lr;
            int c4 = nt * 16 + lq * 4;
            int lvl = (j == 0) ? 0 : (32 - __clz(j));
            floatx4 bp = *(const floatx4*)(bpre + lvl * 64 + c4);
            floatx4 v;
            #pragma unroll
            for (int rg = 0; rg < 4; ++rg) v[rg] = accE[t8][rg] + bp[rg];
            *(floatx4*)(ob + (size_t)j * NF + c4) = v;
        }
        return;
    }

    // ---------- main path: block [n0, n0+128), uniform level L ----------
    const int n0 = nblk * NBLK;

    // Phase E loads (issued first: HBM latency hides under Phase C).
    const float* apA = xb + (size_t)(n0 + 2 * wave * 16 + lr) * NF + lq * 8;
    const float* apB = apA + 16 * NF;         // second M-tile of this wave
    floatx4 fA0 = *(const floatx4*)apA,        fA1 = *(const floatx4*)(apA + 4);
    floatx4 fA2 = *(const floatx4*)(apA + 32), fA3 = *(const floatx4*)(apA + 36);
    floatx4 fB0 = *(const floatx4*)apB,        fB1 = *(const floatx4*)(apB + 4);
    floatx4 fB2 = *(const floatx4*)(apB + 32), fB3 = *(const floatx4*)(apB + 36);

    // Far-table prefetch (independent, L2-resident).
    const int mD  = tid >> 2;                 // 0..63
    const int c0D = (tid & 3) * 16;
    floatx4 fvv[4];
    {
        const float* fv = far + ((size_t)b * 128 + nblk) * 64 + c0D;
        #pragma unroll
        for (int i = 0; i < 4; ++i) fvv[i] = *(const floatx4*)(fv + i * 4);
    }

    // Phase C: ancestor MFMAs (k=1..7). 11 idx-groups x 4 N-tiles; wave w owns
    // idx {w, w+4, w+8}. Transposed acc -> one predicated ds_write_b64 per nt.
    #pragma unroll
    for (int g = 0; g < 3; ++g) {
        const int idx = wave + g * 4;
        const bool gvalid = (idx < 11);
        const int idxc = gvalid ? idx : 0;
        int k, mt;
        if (idxc < 4)       { k = 1; mt = idxc; }
        else if (idxc < 6)  { k = 2; mt = idxc - 4; }
        else if (idxc == 6) { k = 3; mt = 0; }
        else                { k = idxc - 3; mt = 0; }     // k = 4..7
        const int anc = n0 >> k;
        const int rowb = (anc & ~15) + mt * 16;           // 16-row tile base
        const float* ap = xb + (size_t)(rowb + lr) * NF + lq * 8;
        floatx4 f0 = *(const floatx4*)ap,        f1 = *(const floatx4*)(ap + 4);
        floatx4 f2 = *(const floatx4*)(ap + 32), f3 = *(const floatx4*)(ap + 36);
        short8 a0 = cvt8(f0, f1), a1 = cvt8(f2, f3);
        const int tb  = 128 - (256 >> k);     // region base: t1@0,t2@64,...,t7@126
        const int cnt = 128 >> k;
        const int off = anc & 15;             // 0 for k<=3
        int row; bool rvalid;
        if (k <= 3) { row = tb + mt * 16 + lr; rvalid = true; }
        else        { row = tb + lr - off;     rvalid = (lr >= off) && (lr < off + cnt); }
        #pragma unroll
        for (int nt = 0; nt < 4; ++nt) {
            const short* wp = wbf + k * 4096 + (nt * 16 + lr) * 64 + lq * 8;
            short8 b0 = *(const short8*)wp;
            short8 b1 = *(const short8*)(wp + 32);
            floatx4 acc = zero4;
            acc = __builtin_amdgcn_mfma_f32_16x16x32_bf16(b0, a0, acc, 0, 0, 0);
            acc = __builtin_amdgcn_mfma_f32_16x16x32_bf16(b1, a1, acc, 0, 0, 0);
            if (gvalid && rvalid) {
                shortx4 s4;
                s4[0]=f2bf(acc[0]); s4[1]=f2bf(acc[1]); s4[2]=f2bf(acc[2]); s4[3]=f2bf(acc[3]);
                *(shortx4*)(tbuf + row * TROW + nt * 16 + lq * 4) = s4;
            }
        }
    }

    // Phase E MFMAs: k=0, A-fragments reused across the 4 N-tiles.
    floatx4 accE[8];
    {
        short8 aA0 = cvt8(fA0, fA1), aA1 = cvt8(fA2, fA3);
        short8 aB0 = cvt8(fB0, fB1), aB1 = cvt8(fB2, fB3);
        #pragma unroll
        for (int nt = 0; nt < 4; ++nt) {
            const short* wp = wbf + (nt * 16 + lr) * 64 + lq * 8;
            short8 b0 = *(const short8*)wp;
            short8 b1 = *(const short8*)(wp + 32);
            floatx4 accA = zero4, accB = zero4;
            accA = __builtin_amdgcn_mfma_f32_16x16x32_bf16(b0, aA0, accA, 0, 0, 0);
            accA = __builtin_amdgcn_mfma_f32_16x16x32_bf16(b1, aA1, accA, 0, 0, 0);
            accB = __builtin_amdgcn_mfma_f32_16x16x32_bf16(b0, aB0, accB, 0, 0, 0);
            accB = __builtin_amdgcn_mfma_f32_16x16x32_bf16(b1, aB1, accB, 0, 0, 0);
            accE[2 * nt + 0] = accA;
            accE[2 * nt + 1] = accB;
        }
    }
    __syncthreads();

    // Phase D: fold t2..t7 + far into t1 (u1). Vector b128 LDS reads/writes.
    {
        const short* tb0 = tbuf + mD                * TROW + c0D;
        const short* tb1 = tbuf + (64  + (mD >> 1)) * TROW + c0D;
        const short* tb2 = tbuf + (96  + (mD >> 2)) * TROW + c0D;
        const short* tb3 = tbuf + (112 + (mD >> 3)) * TROW + c0D;
        const short* tb4 = tbuf + (120 + (mD >> 4)) * TROW + c0D;
        const short* tb5 = tbuf + (124 + (mD >> 5)) * TROW + c0D;
        const short* tb6 = tbuf + 126               * TROW + c0D;
        short8 r0a = *(const short8*)tb0, r0b = *(const short8*)(tb0 + 8);
        short8 r1a = *(const short8*)tb1, r1b = *(const short8*)(tb1 + 8);
        short8 r2a = *(const short8*)tb2, r2b = *(const short8*)(tb2 + 8);
        short8 r3a = *(const short8*)tb3, r3b = *(const short8*)(tb3 + 8);
        short8 r4a = *(const short8*)tb4, r4b = *(const short8*)(tb4 + 8);
        short8 r5a = *(const short8*)tb5, r5b = *(const short8*)(tb5 + 8);
        short8 r6a = *(const short8*)tb6, r6b = *(const short8*)(tb6 + 8);
        float e[16];
        #pragma unroll
        for (int i = 0; i < 8; ++i) {
            e[i]     = bf2f(r0a[i]) + bf2f(r1a[i]) + bf2f(r2a[i]) + bf2f(r3a[i])
                     + bf2f(r4a[i]) + bf2f(r5a[i]) + bf2f(r6a[i]) + fvv[i >> 2][i & 3];
            e[i + 8] = bf2f(r0b[i]) + bf2f(r1b[i]) + bf2f(r2b[i]) + bf2f(r3b[i])
                     + bf2f(r4b[i]) + bf2f(r5b[i]) + bf2f(r6b[i]) + fvv[(i + 8) >> 2][i & 3];
        }
        __syncthreads();
        short8 wlo, whi;
        #pragma unroll
        for (int i = 0; i < 8; ++i) { wlo[i] = f2bf(e[i]); whi[i] = f2bf(e[i + 8]); }
        *(short8*)(tbuf + mD * TROW + c0D)     = wlo;
        *(short8*)(tbuf + mD * TROW + c0D + 8) = whi;
    }
    __syncthreads();

    // Phase F: out[j] = k0-MFMA + u1[j>>1], dwordx4 store per t8.
    #pragma unroll
    for (int t8 = 0; t8 < 8; ++t8) {
        int mt = 2 * wave + (t8 & 1);
        int nt = t8 >> 1;
        int j  = mt * 16 + lr;
        int c4 = nt * 16 + lq * 4;
        shortx4 u = *(const shortx4*)(tbuf + (mt * 8 + (lr >> 1)) * TROW + c4);
        floatx4 v;
        #pragma unroll
        for (int rg = 0; rg < 4; ++rg) v[rg] = accE[t8][rg] + bf2f(u[rg]);
        *(floatx4*)(ob + (size_t)(n0 + j) * NF + c4) = v;
    }
}

// ---------------------------------------------------------------------------
// Fallback (R2 kernel, passing): used only if ws is too small.
// ---------------------------------------------------------------------------
#define SROW 72
#define SROWS 270
__global__ __launch_bounds__(256, 4)
void heaplin_fallback(const float* __restrict__ x, const float* __restrict__ W,
                      const float* __restrict__ bias, float* __restrict__ out)
{
    __shared__ short stage[SROWS * SROW];
    __shared__ float farpart[4 * 64];
    short* tbuf = stage;
    float* cumB = (float*)(stage + 128 * SROW);

    const int tid  = threadIdx.x;
    const int lane = tid & 63;
    const int wave = tid >> 6;
    const int lr = lane & 15;
    const int lq = lane >> 4;
    const int nblk = blockIdx.x;
    const int b    = blockIdx.y;
    const float* xb = x + (size_t)b * NODES * NF;
    float* ob = out + (size_t)b * NODES * NF;
    const floatx4 zero4 = {0.f, 0.f, 0.f, 0.f};

    if (nblk == 0) {
        if (tid < 64) {
            float run = 0.f;
            for (int k = 0; k < 15; ++k) { run += bias[k * 64 + tid]; cumB[k * 64 + tid] = run; }
        }
        floatx4 accE[8];
        #pragma unroll
        for (int t8 = 0; t8 < 8; ++t8) accE[t8] = zero4;
        for (int k = 0; k < 8; ++k) {
            __syncthreads();
            #pragma unroll
            for (int i = 0; i < 8; ++i) {
                int job = tid + i * 256;
                int r = job >> 4, c4 = job & 15;
                bool valid = (k == 0) || (r >= (1 << (k - 1)));
                floatx4 vv = zero4;
                if (valid) vv = *(const floatx4*)(xb + (r >> k) * NF + c4 * 4);
                shortx4 s4;
                s4[0]=f2bf(vv[0]); s4[1]=f2bf(vv[1]); s4[2]=f2bf(vv[2]); s4[3]=f2bf(vv[3]);
                *(shortx4*)(stage + r * SROW + c4 * 4) = s4;
            }
            __syncthreads();
            #pragma unroll
            for (int t8 = 0; t8 < 8; ++t8) {
                int mt = 2 * wave + (t8 & 1);
                int nt = t8 >> 1;
                int arow = mt * 16 + lr;
                const float* wr = W + k * 4096 + (nt * 16 + lr) * 64 + lq * 8;
                floatx4 wa = *(const floatx4*)wr, wb2 = *(const floatx4*)(wr + 4);
                short8 b0 = cvt8(wa, wb2);
                floatx4 wc = *(const floatx4*)(wr + 32), wd = *(const floatx4*)(wr + 36);
                short8 b1 = cvt8(wc, wd);
                short8 a0 = *(const short8*)(stage + arow * SROW + lq * 8);
                short8 a1 = *(const short8*)(stage + arow * SROW + 32 + lq * 8);
                accE[t8] = __builtin_amdgcn_mfma_f32_16x16x32_bf16(a0, b0, accE[t8], 0, 0, 0);
                accE[t8] = __builtin_amdgcn_mfma_f32_16x16x32_bf16(a1, b1, accE[t8], 0, 0, 0);
            }
        }
        #pragma unroll
        for (int t8 = 0; t8 < 8; ++t8) {
            int mt = 2 * wave + (t8 & 1);
            int nt = t8 >> 1;
            int c = nt * 16 + lr;
            #pragma unroll
            for (int rg = 0; rg < 4; ++rg) {
                int j = mt * 16 + lq * 4 + rg;
                int lvl = (j == 0) ? 0 : (32 - __clz(j));
                ob[(size_t)j * NF + c] = accE[t8][rg] + cumB[lvl * 64 + c];
            }
        }
        return;
    }

    const int n0 = nblk * NBLK;
    const int L  = 32 - __clz(n0);
    floatx4 v[16];
    #pragma unroll
    for (int i = 0; i < 16; ++i) {
        int job = tid + i * 256;
        int r = job >> 4, c4 = job & 15;
        int node;
        if (r < 128)        node = n0 + r;
        else if (r >= 254)  node = n0 >> 7;
        else { int k = __clz(255 - r) - 24; node = (n0 >> k) + r - (256 - (256 >> k)); }
        v[i] = *(const floatx4*)(xb + (size_t)node * NF + c4 * 4);
    }
    #pragma unroll
    for (int i = 0; i < 16; ++i) {
        int job = tid + i * 256;
        int r = job >> 4, c4 = job & 15;
        shortx4 s4;
        s4[0]=f2bf(v[i][0]); s4[1]=f2bf(v[i][1]); s4[2]=f2bf(v[i][2]); s4[3]=f2bf(v[i][3]);
        *(shortx4*)(stage + r * SROW + c4 * 4) = s4;
    }
    __syncthreads();
    floatx4 accE[8];
    #pragma unroll
    for (int t8 = 0; t8 < 8; ++t8) {
        int mt = 2 * wave + (t8 & 1);
        int nt = t8 >> 1;
        int arow = mt * 16 + lr;
        const float* wr = W + (nt * 16 + lr) * 64 + lq * 8;
        floatx4 wa = *(const floatx4*)wr, wb2 = *(const floatx4*)(wr + 4);
        short8 b0 = cvt8(wa, wb2);
        floatx4 wc = *(const floatx4*)(wr + 32), wd = *(const floatx4*)(wr + 36);
        short8 b1 = cvt8(wc, wd);
        short8 a0 = *(const short8*)(stage + arow * SROW + lq * 8);
        short8 a1 = *(const short8*)(stage + arow * SROW + 32 + lq * 8);
        floatx4 acc = zero4;
        acc = __builtin_amdgcn_mfma_f32_16x16x32_bf16(a0, b0, acc, 0, 0, 0);
        acc = __builtin_amdgcn_mfma_f32_16x16x32_bf16(a1, b1, acc, 0, 0, 0);
        accE[t8] = acc;
    }
    {
        float p = 0.f;
        const int q = wave, o = lane;
        for (int k = 8; k <= L; ++k) {
            const float* xa = xb + (size_t)(n0 >> k) * NF + q * 16;
            const float* wr = W + k * 4096 + o * 64 + q * 16;
            #pragma unroll
            for (int i = 0; i < 4; ++i) {
                floatx4 wv = *(const floatx4*)(wr + i * 4);
                floatx4 xv = *(const floatx4*)(xa + i * 4);
                p += wv[0]*xv[0] + wv[1]*xv[1] + wv[2]*xv[2] + wv[3]*xv[3];
            }
        }
        if (q == 0) for (int k = 0; k <= L; ++k) p += bias[k * 64 + o];
        farpart[q * 64 + o] = p;
    }
    __syncthreads();
    for (int jj = 0; jj < 11; ++jj) {
        int job = wave + jj * 4;
        int idx = job % 11;
        int nt  = job / 11;
        int k, mt;
        if (idx < 4)      { k = 1; mt = idx; }
        else if (idx < 6) { k = 2; mt = idx - 4; }
        else if (idx < 7) { k = 3; mt = 0; }
        else              { k = idx - 3; mt = 0; }
        int sbase = 256 - (256 >> k);
        int arow = sbase + mt * 16 + lr;
        const float* wr = W + k * 4096 + (nt * 16 + lr) * 64 + lq * 8;
        floatx4 wa = *(const floatx4*)wr, wb2 = *(const floatx4*)(wr + 4);
        short8 b0 = cvt8(wa, wb2);
        floatx4 wc = *(const floatx4*)(wr + 32), wd = *(const floatx4*)(wr + 36);
        short8 b1 = cvt8(wc, wd);
        short8 a0 = *(const short8*)(stage + arow * SROW + lq * 8);
        short8 a1 = *(const short8*)(stage + arow * SROW + 32 + lq * 8);
        floatx4 acc = zero4;
        acc = __builtin_amdgcn_mfma_f32_16x16x32_bf16(a0, b0, acc, 0, 0, 0);
        acc = __builtin_amdgcn_mfma_f32_16x16x32_bf16(a1, b1, acc, 0, 0, 0);
        int tb = 128 - (256 >> k);
        int nvalid = 128 >> k;
        #pragma unroll
        for (int rg = 0; rg < 4; ++rg) {
            int m = mt * 16 + lq * 4 + rg;
            if (m < nvalid) tbuf[(tb + m) * TROW + nt * 16 + lr] = f2bf(acc[rg]);
        }
    }
    __syncthreads();
    {
        int m  = tid >> 2;
        int c0 = (tid & 3) * 16;
        float e[16];
        #pragma unroll
        for (int i = 0; i < 16; ++i) {
            int c = c0 + i;
            e[i] = bf2f(tbuf[ m               * TROW + c])
                 + bf2f(tbuf[(64  + (m >> 1)) * TROW + c])
                 + bf2f(tbuf[(96  + (m >> 2)) * TROW + c])
                 + bf2f(tbuf[(112 + (m >> 3)) * TROW + c])
                 + bf2f(tbuf[(120 + (m >> 4)) * TROW + c])
                 + bf2f(tbuf[(124 + (m >> 5)) * TROW + c])
                 + bf2f(tbuf[126              * TROW + c])
                 + farpart[c] + farpart[64 + c] + farpart[128 + c] + farpart[192 + c];
        }
        #pragma unroll
        for (int i = 0; i < 16; ++i) tbuf[m * TROW + c0 + i] = f2bf(e[i]);
    }
    __syncthreads();
    #pragma unroll
    for (int t8 = 0; t8 < 8; ++t8) {
        int mt = 2 * wave + (t8 & 1);
        int nt = t8 >> 1;
        int c = nt * 16 + lr;
        #pragma unroll
        for (int rg = 0; rg < 4; ++rg) {
            int j = mt * 16 + lq * 4 + rg;
            float val = accE[t8][rg] + bf2f(tbuf[(j >> 1) * TROW + c]);
            ob[(size_t)(n0 + j) * NF + c] = val;
        }
    }
}

extern "C" void kernel_launch(void* const* d_in, const int* in_sizes, int n_in,
                              void* d_out, int out_size, void* d_ws, size_t ws_size,
                              hipStream_t stream) {
    const float* x  = (const float*)d_in[0];   // [32][16384][64]
    const float* W  = (const float*)d_in[1];   // [15][64][64]
    const float* bs = (const float*)d_in[2];   // [15][64]
    float* out = (float*)d_out;                // [32][16384][64]
    dim3 grid(NODES / NBLK, BATCH);
    if (ws_size >= WS_NEEDED) {
        short* wbf  = (short*)((char*)d_ws + WS_WBF_OFF);
        float* wt   = (float*)((char*)d_ws + WS_WT_OFF);
        float* bpre = (float*)((char*)d_ws + WS_BPRE_OFF);
        float* farb = (float*)((char*)d_ws + WS_FAR_OFF);
        heaplin_prep1<<<46, 256, 0, stream>>>(W, bs, wbf, wt, bpre);
        heaplin_prep2<<<32, 256, 0, stream>>>(x, wt, bpre, farb);
        heaplin_main<<<grid, 256, 0, stream>>>(x, wbf, farb, bpre, out);
    } else {
        heaplin_fallback<<<grid, 256, 0, stream>>>(x, W, bs, out);
    }
}

// Round 4
// 327.881 us; speedup vs baseline: 1.0491x; 1.0491x over previous
//
#include <hip/hip_runtime.h>

#define NODES 16384
#define NF 64
#define NBLK 128          // nodes per workgroup (main kernel)
#define TROW 72           // shorts per tile/tbuf row (64 data + 8 pad) = 144 B
#define BATCH 32
#define NTILES 19         // 8 E-tiles + 4(k=1) + 2(k=2) + 1(k=3) + 4(k=4..7)

// ws layout (bytes):
//   wbf  bf16 @0        (122,880)
//   wt   fp32 @122,880  (245,760)   W^T per level: [k][i][o]
//   bpre fp32 @368,640  (3,840)
//   far  fp32 @372,480  (1,048,576) per (b, nblk): sum_{k=8..L} W_k@x[n0>>k] + bpre[L]
#define WS_WBF_OFF   0ull
#define WS_WT_OFF    122880ull
#define WS_BPRE_OFF  368640ull
#define WS_FAR_OFF   372480ull
#define WS_NEEDED    1421056ull

typedef __attribute__((ext_vector_type(8))) short short8;
typedef __attribute__((ext_vector_type(4))) short shortx4;
typedef __attribute__((ext_vector_type(4))) float floatx4;

__device__ __forceinline__ short f2bf(float f) {
    unsigned u = __float_as_uint(f);
    u += 0x7fffu + ((u >> 16) & 1u);          // RTNE (inputs finite)
    return (short)(u >> 16);
}
__device__ __forceinline__ float bf2f(short s) {
    return __uint_as_float(((unsigned)(unsigned short)s) << 16);
}
__device__ __forceinline__ short8 cvt8(floatx4 a, floatx4 c) {
    short8 r;
    r[0]=f2bf(a[0]); r[1]=f2bf(a[1]); r[2]=f2bf(a[2]); r[3]=f2bf(a[3]);
    r[4]=f2bf(c[0]); r[5]=f2bf(c[1]); r[6]=f2bf(c[2]); r[7]=f2bf(c[3]);
    return r;
}

// Staged-tile table: t 0..7 = E rows n0+16t; 8..11 = k=1; 12..13 = k=2;
// 14 = k=3; 15..18 = k=4..7 (aligned 16-row tile containing the ancestors).
__device__ __forceinline__ int tile_base(int t, int n0) {
    if (t < 8)   return n0 + t * 16;
    if (t < 12)  return (n0 >> 1) + (t - 8) * 16;
    if (t < 14)  return (n0 >> 2) + (t - 12) * 16;
    if (t == 14) return (n0 >> 3);
    int k = t - 11;                       // 4..7
    return (n0 >> k) & ~15;
}

// ---------------------------------------------------------------------------
// prep1: W fp32 -> bf16 (blocks 0..29), bias prefix (block 30),
//        W^T fp32 [k][i][o] (blocks 31..45) for coalesced matvecs in prep2.
// ---------------------------------------------------------------------------
__global__ __launch_bounds__(256)
void heaplin_prep1(const float* __restrict__ W, const float* __restrict__ bias,
                   short* __restrict__ wbf, float* __restrict__ wt,
                   float* __restrict__ bpre)
{
    const int blk = blockIdx.x;
    const int tid = threadIdx.x;
    if (blk < 30) {
        int e = blk * 2048 + tid * 8;        // [0, 61440)
        floatx4 a = *(const floatx4*)(W + e);
        floatx4 c = *(const floatx4*)(W + e + 4);
        *(short8*)(wbf + e) = cvt8(a, c);
    } else if (blk == 30) {
        if (tid < 64) {
            float run = 0.f;
            for (int k = 0; k < 15; ++k) { run += bias[k * 64 + tid]; bpre[k * 64 + tid] = run; }
        }
    } else {
        int k = blk - 31;                    // 0..14
        #pragma unroll
        for (int it = 0; it < 16; ++it) {
            int idx = tid + it * 256;        // [0, 4096)
            int o = idx >> 6, i = idx & 63;
            wt[k * 4096 + i * 64 + o] = W[k * 4096 + idx];
        }
    }
}

// ---------------------------------------------------------------------------
// prep2: far-ancestor table, fp32-exact (precision-critical path).
// ---------------------------------------------------------------------------
__global__ __launch_bounds__(256)
void heaplin_prep2(const float* __restrict__ x, const float* __restrict__ wt,
                   const float* __restrict__ bpre, float* __restrict__ far)
{
    __shared__ float xl[64 * 64];            // x rows 0..63
    __shared__ float Zl[127 * 64];           // packed Z rows
    const int tid = threadIdx.x;
    const int b   = blockIdx.x;
    const float* xb = x + (size_t)b * NODES * NF;

    #pragma unroll
    for (int i = 0; i < 4; ++i) {            // stage 16 KB coalesced
        int job = tid + i * 256;             // 1024 floatx4 jobs
        *(floatx4*)(xl + job * 4) = *(const floatx4*)(xb + job * 4);
    }
    __syncthreads();

    const int wave = tid >> 6, lane = tid & 63;
    const int o4 = lane & 15, j = lane >> 4;
    for (int r = wave; r < 127; r += 4) {
        int t, a;
        if (r < 64)       { t = 1; a = r; }
        else if (r < 96)  { t = 2; a = r - 64; }
        else if (r < 112) { t = 3; a = r - 96; }
        else if (r < 120) { t = 4; a = r - 112; }
        else if (r < 124) { t = 5; a = r - 120; }
        else if (r < 126) { t = 6; a = r - 124; }
        else              { t = 7; a = 0; }
        const float* wtk = wt + (7 + t) * 4096;
        floatx4 acc = {0.f, 0.f, 0.f, 0.f};
        #pragma unroll
        for (int i16 = 0; i16 < 16; ++i16) {
            int i = j + i16 * 4;             // j splits the i-dim 4 ways
            floatx4 w4 = *(const floatx4*)(wtk + i * 64 + o4 * 4);
            float xs = xl[a * 64 + i];
            acc[0] += w4[0]*xs; acc[1] += w4[1]*xs; acc[2] += w4[2]*xs; acc[3] += w4[3]*xs;
        }
        #pragma unroll
        for (int c = 0; c < 4; ++c) {        // reduce over j (lanes ^16, ^32)
            acc[c] += __shfl_xor(acc[c], 16, 64);
            acc[c] += __shfl_xor(acc[c], 32, 64);
        }
        if (j == 0) *(floatx4*)(Zl + r * 64 + o4 * 4) = acc;
    }
    __syncthreads();

    for (int it = 0; it < 32; ++it) {
        int job = tid + it * 256;
        if (job < 127 * 64) {
            int m = 1 + (job >> 6), o = job & 63;
            int bl = 32 - __clz(m);          // 1..7
            float s = bpre[(7 + bl) * 64 + o];
            #pragma unroll
            for (int t = 1; t <= 7; ++t)
                if (t <= bl) s += Zl[(128 - (128 >> (t - 1)) + (m >> t)) * 64 + o];
            far[((size_t)b * 128 + m) * 64 + o] = s;
        }
    }
}

// ---------------------------------------------------------------------------
// Main kernel. Latency fix: ALL x reads happen in one coalesced bulk-stage
// prologue (20 back-to-back dwordx4 per wave, contiguous 1 KB per instr),
// converted to bf16 into 19 LDS tiles. MFMA fragments read from LDS.
// t1..t7 fold buffer OVERLAYS the E-tile region (E MFMAs consume it first).
// MFMAs use swapped operands -> lane owns (node row lr, 4 feature cols).
// LDS 43.8 KB -> 3 blocks/CU.
// ---------------------------------------------------------------------------
__global__ __launch_bounds__(256, 3)
void heaplin_main(const float* __restrict__ x, const short* __restrict__ wbf,
                  const float* __restrict__ far, const float* __restrict__ bpre,
                  float* __restrict__ out)
{
    __shared__ short stage[NTILES * 16 * TROW];   // 43,776 B; tbuf overlays tiles 0..7
    short* tbuf = stage;                          // t1..t7 rows 0..126 (after Phase E)

    const int tid  = threadIdx.x;
    const int lane = tid & 63;
    const int wave = tid >> 6;
    const int lr = lane & 15;
    const int lq = lane >> 4;
    const int nblk = blockIdx.x;
    const int b    = blockIdx.y;
    const float* xb = x + (size_t)b * NODES * NF;
    float* ob = out + (size_t)b * NODES * NF;
    const floatx4 zero4 = {0.f, 0.f, 0.f, 0.f};

    if (nblk == 0) {
        // ---------- block-0 path: nodes 0..127 span levels 0..7 (masked) ----------
        floatx4 accE[8];
        #pragma unroll
        for (int t8 = 0; t8 < 8; ++t8) accE[t8] = zero4;

        for (int k = 0; k < 8; ++k) {
            __syncthreads();
            #pragma unroll
            for (int i = 0; i < 8; ++i) {    // 2048 jobs: stage row j = x[j>>k] or 0
                int job = tid + i * 256;
                int r = job >> 4, c4 = job & 15;
                bool valid = (k == 0) || (r >= (1 << (k - 1)));
                floatx4 vv = zero4;
                if (valid) vv = *(const floatx4*)(xb + (r >> k) * NF + c4 * 4);
                shortx4 s4;
                s4[0]=f2bf(vv[0]); s4[1]=f2bf(vv[1]); s4[2]=f2bf(vv[2]); s4[3]=f2bf(vv[3]);
                *(shortx4*)(tbuf + r * TROW + c4 * 4) = s4;
            }
            __syncthreads();
            #pragma unroll
            for (int t8 = 0; t8 < 8; ++t8) {
                int mt = 2 * wave + (t8 & 1);
                int nt = t8 >> 1;
                int arow = mt * 16 + lr;
                const short* wp = wbf + k * 4096 + (nt * 16 + lr) * 64 + lq * 8;
                short8 b0 = *(const short8*)wp;
                short8 b1 = *(const short8*)(wp + 32);
                short8 a0 = *(const short8*)(tbuf + arow * TROW + lq * 8);
                short8 a1 = *(const short8*)(tbuf + arow * TROW + 32 + lq * 8);
                accE[t8] = __builtin_amdgcn_mfma_f32_16x16x32_bf16(b0, a0, accE[t8], 0, 0, 0);
                accE[t8] = __builtin_amdgcn_mfma_f32_16x16x32_bf16(b1, a1, accE[t8], 0, 0, 0);
            }
        }
        #pragma unroll
        for (int t8 = 0; t8 < 8; ++t8) {
            int mt = 2 * wave + (t8 & 1);
            int nt = t8 >> 1;
            int j  = mt * 16 + lr;
            int c4 = nt * 16 + lq * 4;
            int lvl = (j == 0) ? 0 : (32 - __clz(j));
            floatx4 bp = *(const floatx4*)(bpre + lvl * 64 + c4);
            floatx4 v;
            #pragma unroll
            for (int rg = 0; rg < 4; ++rg) v[rg] = accE[t8][rg] + bp[rg];
            *(floatx4*)(ob + (size_t)j * NF + c4) = v;
        }
        return;
    }

    // ---------- main path: block [n0, n0+128), uniform level L ----------
    const int n0 = nblk * NBLK;

    // Bulk stage: wave w owns tiles [5w, 5w+5) (clamped; dup of t18 is benign,
    // same wave writes same data). 20 coalesced dwordx4 issued back-to-back.
    floatx4 sv[20];
    #pragma unroll
    for (int i = 0; i < 5; ++i) {
        int t = wave * 5 + i; if (t > 18) t = 18;
        const float* src = xb + (size_t)(tile_base(t, n0) + (lane >> 4)) * NF + (lane & 15) * 4;
        #pragma unroll
        for (int it = 0; it < 4; ++it)
            sv[i * 4 + it] = *(const floatx4*)(src + it * 4 * NF);
    }

    // Far-table prefetch (independent, L2-resident).
    const int mD  = tid >> 2;                 // 0..63
    const int c0D = (tid & 3) * 16;
    floatx4 fvv[4];
    {
        const float* fv = far + ((size_t)b * 128 + nblk) * 64 + c0D;
        #pragma unroll
        for (int i = 0; i < 4; ++i) fvv[i] = *(const floatx4*)(fv + i * 4);
    }

    // Convert + LDS write (conflict-free: b64, rows padded to 144 B).
    #pragma unroll
    for (int i = 0; i < 5; ++i) {
        int t = wave * 5 + i; if (t > 18) t = 18;
        #pragma unroll
        for (int it = 0; it < 4; ++it) {
            floatx4 v = sv[i * 4 + it];
            shortx4 s4;
            s4[0]=f2bf(v[0]); s4[1]=f2bf(v[1]); s4[2]=f2bf(v[2]); s4[3]=f2bf(v[3]);
            *(shortx4*)(stage + (t * 16 + it * 4 + (lane >> 4)) * TROW + (lane & 15) * 4) = s4;
        }
    }
    __syncthreads();

    // Phase E: k=0 MFMAs from LDS tiles 2w, 2w+1; A-frags reused across 4 nt.
    floatx4 accE[8];
    {
        const short* pa = stage + ((2 * wave)     * 16 + lr) * TROW + lq * 8;
        const short* pb = stage + ((2 * wave + 1) * 16 + lr) * TROW + lq * 8;
        short8 aA0 = *(const short8*)pa, aA1 = *(const short8*)(pa + 32);
        short8 aB0 = *(const short8*)pb, aB1 = *(const short8*)(pb + 32);
        #pragma unroll
        for (int nt = 0; nt < 4; ++nt) {
            const short* wp = wbf + (nt * 16 + lr) * 64 + lq * 8;
            short8 b0 = *(const short8*)wp;
            short8 b1 = *(const short8*)(wp + 32);
            floatx4 accA = zero4, accB = zero4;
            accA = __builtin_amdgcn_mfma_f32_16x16x32_bf16(b0, aA0, accA, 0, 0, 0);
            accA = __builtin_amdgcn_mfma_f32_16x16x32_bf16(b1, aA1, accA, 0, 0, 0);
            accB = __builtin_amdgcn_mfma_f32_16x16x32_bf16(b0, aB0, accB, 0, 0, 0);
            accB = __builtin_amdgcn_mfma_f32_16x16x32_bf16(b1, aB1, accB, 0, 0, 0);
            accE[2 * nt + 0] = accA;
            accE[2 * nt + 1] = accB;
        }
    }
    __syncthreads();   // all E-tile reads done before tbuf overlay writes

    // Phase C: ancestor MFMAs (k=1..7) from LDS tiles 8..18; writes overlay
    // tbuf rows 0..126 (disjoint from tiles 8..18). 11 idx-groups x 4 nt.
    #pragma unroll
    for (int g = 0; g < 3; ++g) {
        const int idx = wave + g * 4;
        const bool gvalid = (idx < 11);
        const int idxc = gvalid ? idx : 0;
        int k, mt, tIdx;
        if (idxc < 4)       { k = 1; mt = idxc;     tIdx = 8 + mt; }
        else if (idxc < 6)  { k = 2; mt = idxc - 4; tIdx = 12 + mt; }
        else if (idxc == 6) { k = 3; mt = 0;        tIdx = 14; }
        else                { k = idxc - 3; mt = 0; tIdx = 11 + k; }   // k = 4..7
        const int anc = n0 >> k;
        const short* pa = stage + (tIdx * 16 + lr) * TROW + lq * 8;
        short8 a0 = *(const short8*)pa, a1 = *(const short8*)(pa + 32);
        const int tb  = 128 - (256 >> k);     // region base: t1@0,t2@64,...,t7@126
        const int cnt = 128 >> k;
        const int off = anc & 15;             // 0 for k<=3
        int row; bool rvalid;
        if (k <= 3) { row = tb + mt * 16 + lr; rvalid = true; }
        else        { row = tb + lr - off;     rvalid = (lr >= off) && (lr < off + cnt); }
        #pragma unroll
        for (int nt = 0; nt < 4; ++nt) {
            const short* wp = wbf + k * 4096 + (nt * 16 + lr) * 64 + lq * 8;
            short8 b0 = *(const short8*)wp;
            short8 b1 = *(const short8*)(wp + 32);
            floatx4 acc = zero4;
            acc = __builtin_amdgcn_mfma_f32_16x16x32_bf16(b0, a0, acc, 0, 0, 0);
            acc = __builtin_amdgcn_mfma_f32_16x16x32_bf16(b1, a1, acc, 0, 0, 0);
            if (gvalid && rvalid) {
                shortx4 s4;
                s4[0]=f2bf(acc[0]); s4[1]=f2bf(acc[1]); s4[2]=f2bf(acc[2]); s4[3]=f2bf(acc[3]);
                *(shortx4*)(tbuf + row * TROW + nt * 16 + lq * 4) = s4;
            }
        }
    }
    __syncthreads();

    // Phase D: fold t2..t7 + far into t1 (u1). 4 col-chunks of 4 to keep VGPR
    // low; each (row,col) of t1 is read+written by the same thread (no race).
    #pragma unroll
    for (int q = 0; q < 4; ++q) {
        const int cq = c0D + q * 4;
        shortx4 r0 = *(const shortx4*)(tbuf +  mD               * TROW + cq);
        shortx4 r1 = *(const shortx4*)(tbuf + (64  + (mD >> 1)) * TROW + cq);
        shortx4 r2 = *(const shortx4*)(tbuf + (96  + (mD >> 2)) * TROW + cq);
        shortx4 r3 = *(const shortx4*)(tbuf + (112 + (mD >> 3)) * TROW + cq);
        shortx4 r4 = *(const shortx4*)(tbuf + (120 + (mD >> 4)) * TROW + cq);
        shortx4 r5 = *(const shortx4*)(tbuf + (124 + (mD >> 5)) * TROW + cq);
        shortx4 r6 = *(const shortx4*)(tbuf + 126               * TROW + cq);
        shortx4 w;
        #pragma unroll
        for (int i = 0; i < 4; ++i) {
            float e = bf2f(r0[i]) + bf2f(r1[i]) + bf2f(r2[i]) + bf2f(r3[i])
                    + bf2f(r4[i]) + bf2f(r5[i]) + bf2f(r6[i]) + fvv[q][i];
            w[i] = f2bf(e);
        }
        *(shortx4*)(tbuf + mD * TROW + cq) = w;
    }
    __syncthreads();

    // Phase F: out[j] = k0-MFMA + u1[j>>1], dwordx4 store per t8.
    #pragma unroll
    for (int t8 = 0; t8 < 8; ++t8) {
        int mt = 2 * wave + (t8 & 1);
        int nt = t8 >> 1;
        int j  = mt * 16 + lr;
        int c4 = nt * 16 + lq * 4;
        shortx4 u = *(const shortx4*)(tbuf + (mt * 8 + (lr >> 1)) * TROW + c4);
        floatx4 v;
        #pragma unroll
        for (int rg = 0; rg < 4; ++rg) v[rg] = accE[t8][rg] + bf2f(u[rg]);
        *(floatx4*)(ob + (size_t)(n0 + j) * NF + c4) = v;
    }
}

// ---------------------------------------------------------------------------
// Fallback (R2 kernel, passing): used only if ws is too small.
// ---------------------------------------------------------------------------
#define SROW 72
#define SROWS 270
__global__ __launch_bounds__(256, 4)
void heaplin_fallback(const float* __restrict__ x, const float* __restrict__ W,
                      const float* __restrict__ bias, float* __restrict__ out)
{
    __shared__ short stage[SROWS * SROW];
    __shared__ float farpart[4 * 64];
    short* tbuf = stage;
    float* cumB = (float*)(stage + 128 * SROW);

    const int tid  = threadIdx.x;
    const int lane = tid & 63;
    const int wave = tid >> 6;
    const int lr = lane & 15;
    const int lq = lane >> 4;
    const int nblk = blockIdx.x;
    const int b    = blockIdx.y;
    const float* xb = x + (size_t)b * NODES * NF;
    float* ob = out + (size_t)b * NODES * NF;
    const floatx4 zero4 = {0.f, 0.f, 0.f, 0.f};

    if (nblk == 0) {
        if (tid < 64) {
            float run = 0.f;
            for (int k = 0; k < 15; ++k) { run += bias[k * 64 + tid]; cumB[k * 64 + tid] = run; }
        }
        floatx4 accE[8];
        #pragma unroll
        for (int t8 = 0; t8 < 8; ++t8) accE[t8] = zero4;
        for (int k = 0; k < 8; ++k) {
            __syncthreads();
            #pragma unroll
            for (int i = 0; i < 8; ++i) {
                int job = tid + i * 256;
                int r = job >> 4, c4 = job & 15;
                bool valid = (k == 0) || (r >= (1 << (k - 1)));
                floatx4 vv = zero4;
                if (valid) vv = *(const floatx4*)(xb + (r >> k) * NF + c4 * 4);
                shortx4 s4;
                s4[0]=f2bf(vv[0]); s4[1]=f2bf(vv[1]); s4[2]=f2bf(vv[2]); s4[3]=f2bf(vv[3]);
                *(shortx4*)(stage + r * SROW + c4 * 4) = s4;
            }
            __syncthreads();
            #pragma unroll
            for (int t8 = 0; t8 < 8; ++t8) {
                int mt = 2 * wave + (t8 & 1);
                int nt = t8 >> 1;
                int arow = mt * 16 + lr;
                const float* wr = W + k * 4096 + (nt * 16 + lr) * 64 + lq * 8;
                floatx4 wa = *(const floatx4*)wr, wb2 = *(const floatx4*)(wr + 4);
                short8 b0 = cvt8(wa, wb2);
                floatx4 wc = *(const floatx4*)(wr + 32), wd = *(const floatx4*)(wr + 36);
                short8 b1 = cvt8(wc, wd);
                short8 a0 = *(const short8*)(stage + arow * SROW + lq * 8);
                short8 a1 = *(const short8*)(stage + arow * SROW + 32 + lq * 8);
                accE[t8] = __builtin_amdgcn_mfma_f32_16x16x32_bf16(a0, b0, accE[t8], 0, 0, 0);
                accE[t8] = __builtin_amdgcn_mfma_f32_16x16x32_bf16(a1, b1, accE[t8], 0, 0, 0);
            }
        }
        #pragma unroll
        for (int t8 = 0; t8 < 8; ++t8) {
            int mt = 2 * wave + (t8 & 1);
            int nt = t8 >> 1;
            int c = nt * 16 + lr;
            #pragma unroll
            for (int rg = 0; rg < 4; ++rg) {
                int j = mt * 16 + lq * 4 + rg;
                int lvl = (j == 0) ? 0 : (32 - __clz(j));
                ob[(size_t)j * NF + c] = accE[t8][rg] + cumB[lvl * 64 + c];
            }
        }
        return;
    }

    const int n0 = nblk * NBLK;
    const int L  = 32 - __clz(n0);
    floatx4 v[16];
    #pragma unroll
    for (int i = 0; i < 16; ++i) {
        int job = tid + i * 256;
        int r = job >> 4, c4 = job & 15;
        int node;
        if (r < 128)        node = n0 + r;
        else if (r >= 254)  node = n0 >> 7;
        else { int k = __clz(255 - r) - 24; node = (n0 >> k) + r - (256 - (256 >> k)); }
        v[i] = *(const floatx4*)(xb + (size_t)node * NF + c4 * 4);
    }
    #pragma unroll
    for (int i = 0; i < 16; ++i) {
        int job = tid + i * 256;
        int r = job >> 4, c4 = job & 15;
        shortx4 s4;
        s4[0]=f2bf(v[i][0]); s4[1]=f2bf(v[i][1]); s4[2]=f2bf(v[i][2]); s4[3]=f2bf(v[i][3]);
        *(shortx4*)(stage + r * SROW + c4 * 4) = s4;
    }
    __syncthreads();
    floatx4 accE[8];
    #pragma unroll
    for (int t8 = 0; t8 < 8; ++t8) {
        int mt = 2 * wave + (t8 & 1);
        int nt = t8 >> 1;
        int arow = mt * 16 + lr;
        const float* wr = W + (nt * 16 + lr) * 64 + lq * 8;
        floatx4 wa = *(const floatx4*)wr, wb2 = *(const floatx4*)(wr + 4);
        short8 b0 = cvt8(wa, wb2);
        floatx4 wc = *(const floatx4*)(wr + 32), wd = *(const floatx4*)(wr + 36);
        short8 b1 = cvt8(wc, wd);
        short8 a0 = *(const short8*)(stage + arow * SROW + lq * 8);
        short8 a1 = *(const short8*)(stage + arow * SROW + 32 + lq * 8);
        floatx4 acc = zero4;
        acc = __builtin_amdgcn_mfma_f32_16x16x32_bf16(a0, b0, acc, 0, 0, 0);
        acc = __builtin_amdgcn_mfma_f32_16x16x32_bf16(a1, b1, acc, 0, 0, 0);
        accE[t8] = acc;
    }
    {
        float p = 0.f;
        const int q = wave, o = lane;
        for (int k = 8; k <= L; ++k) {
            const float* xa = xb + (size_t)(n0 >> k) * NF + q * 16;
            const float* wr = W + k * 4096 + o * 64 + q * 16;
            #pragma unroll
            for (int i = 0; i < 4; ++i) {
                floatx4 wv = *(const floatx4*)(wr + i * 4);
                floatx4 xv = *(const floatx4*)(xa + i * 4);
                p += wv[0]*xv[0] + wv[1]*xv[1] + wv[2]*xv[2] + wv[3]*xv[3];
            }
        }
        if (q == 0) for (int k = 0; k <= L; ++k) p += bias[k * 64 + o];
        farpart[q * 64 + o] = p;
    }
    __syncthreads();
    for (int jj = 0; jj < 11; ++jj) {
        int job = wave + jj * 4;
        int idx = job % 11;
        int nt  = job / 11;
        int k, mt;
        if (idx < 4)      { k = 1; mt = idx; }
        else if (idx < 6) { k = 2; mt = idx - 4; }
        else if (idx < 7) { k = 3; mt = 0; }
        else              { k = idx - 3; mt = 0; }
        int sbase = 256 - (256 >> k);
        int arow = sbase + mt * 16 + lr;
        const float* wr = W + k * 4096 + (nt * 16 + lr) * 64 + lq * 8;
        floatx4 wa = *(const floatx4*)wr, wb2 = *(const floatx4*)(wr + 4);
        short8 b0 = cvt8(wa, wb2);
        floatx4 wc = *(const floatx4*)(wr + 32), wd = *(const floatx4*)(wr + 36);
        short8 b1 = cvt8(wc, wd);
        short8 a0 = *(const short8*)(stage + arow * SROW + lq * 8);
        short8 a1 = *(const short8*)(stage + arow * SROW + 32 + lq * 8);
        floatx4 acc = zero4;
        acc = __builtin_amdgcn_mfma_f32_16x16x32_bf16(a0, b0, acc, 0, 0, 0);
        acc = __builtin_amdgcn_mfma_f32_16x16x32_bf16(a1, b1, acc, 0, 0, 0);
        int tb = 128 - (256 >> k);
        int nvalid = 128 >> k;
        #pragma unroll
        for (int rg = 0; rg < 4; ++rg) {
            int m = mt * 16 + lq * 4 + rg;
            if (m < nvalid) tbuf[(tb + m) * TROW + nt * 16 + lr] = f2bf(acc[rg]);
        }
    }
    __syncthreads();
    {
        int m  = tid >> 2;
        int c0 = (tid & 3) * 16;
        float e[16];
        #pragma unroll
        for (int i = 0; i < 16; ++i) {
            int c = c0 + i;
            e[i] = bf2f(tbuf[ m               * SROW + c])
                 + bf2f(tbuf[(64  + (m >> 1)) * SROW + c])
                 + bf2f(tbuf[(96  + (m >> 2)) * SROW + c])
                 + bf2f(tbuf[(112 + (m >> 3)) * SROW + c])
                 + bf2f(tbuf[(120 + (m >> 4)) * SROW + c])
                 + bf2f(tbuf[(124 + (m >> 5)) * SROW + c])
                 + bf2f(tbuf[126              * SROW + c])
                 + farpart[c] + farpart[64 + c] + farpart[128 + c] + farpart[192 + c];
        }
        #pragma unroll
        for (int i = 0; i < 16; ++i) tbuf[m * SROW + c0 + i] = f2bf(e[i]);
    }
    __syncthreads();
    #pragma unroll
    for (int t8 = 0; t8 < 8; ++t8) {
        int mt = 2 * wave + (t8 & 1);
        int nt = t8 >> 1;
        int c = nt * 16 + lr;
        #pragma unroll
        for (int rg = 0; rg < 4; ++rg) {
            int j = mt * 16 + lq * 4 + rg;
            float val = accE[t8][rg] + bf2f(tbuf[(j >> 1) * SROW + c]);
            ob[(size_t)(n0 + j) * NF + c] = val;
        }
    }
}

extern "C" void kernel_launch(void* const* d_in, const int* in_sizes, int n_in,
                              void* d_out, int out_size, void* d_ws, size_t ws_size,
                              hipStream_t stream) {
    const float* x  = (const float*)d_in[0];   // [32][16384][64]
    const float* W  = (const float*)d_in[1];   // [15][64][64]
    const float* bs = (const float*)d_in[2];   // [15][64]
    float* out = (float*)d_out;                // [32][16384][64]
    dim3 grid(NODES / NBLK, BATCH);
    if (ws_size >= WS_NEEDED) {
        short* wbf  = (short*)((char*)d_ws + WS_WBF_OFF);
        float* wt   = (float*)((char*)d_ws + WS_WT_OFF);
        float* bpre = (float*)((char*)d_ws + WS_BPRE_OFF);
        float* farb = (float*)((char*)d_ws + WS_FAR_OFF);
        heaplin_prep1<<<46, 256, 0, stream>>>(W, bs, wbf, wt, bpre);
        heaplin_prep2<<<32, 256, 0, stream>>>(x, wt, bpre, farb);
        heaplin_main<<<grid, 256, 0, stream>>>(x, wbf, farb, bpre, out);
    } else {
        heaplin_fallback<<<grid, 256, 0, stream>>>(x, W, bs, out);
    }
}